// Round 1
// baseline (746.619 us; speedup 1.0000x reference)
//
#include <hip/hip_runtime.h>
#include <cstddef>

#define HH 16
#define TT 512
#define LOG2E 1.44269504088896340736f

// ---- fast scalar helpers (native v_exp_f32 / v_rcp_f32 / v_rsq_f32) ----
__device__ __forceinline__ float fexp2(float x) {
#if __has_builtin(__builtin_amdgcn_exp2f)
    return __builtin_amdgcn_exp2f(x);
#else
    return exp2f(x);
#endif
}
__device__ __forceinline__ float frcp(float x) {
#if __has_builtin(__builtin_amdgcn_rcpf)
    return __builtin_amdgcn_rcpf(x);
#else
    return 1.0f / x;
#endif
}
__device__ __forceinline__ float frsq(float x) {
#if __has_builtin(__builtin_amdgcn_rsqf)
    return __builtin_amdgcn_rsqf(x);
#else
    return rsqrtf(x);
#endif
}

// tanh(c) = 2/(1+exp(-2c)) - 1 ; saturates correctly (rcp(inf)=0)
__device__ __forceinline__ float ftanh(float c) {
    float e = fexp2(c * (-2.0f * LOG2E));
    return frcp(1.0f + e) * 2.0f - 1.0f;
}

// broadcast within each quad of lanes (VALU DPP, no LDS pipe)
template <int CTRL>
__device__ __forceinline__ float quad_bcast(float v) {
    return __builtin_bit_cast(float,
        __builtin_amdgcn_update_dpp(0, __builtin_bit_cast(int, v),
                                    CTRL, 0xF, 0xF, true));
}

// readlane -> wave-uniform (SGPR) value
__device__ __forceinline__ float rl(float v, int lane) {
    return __builtin_bit_cast(float,
        __builtin_amdgcn_readlane(__builtin_bit_cast(int, v), lane));
}

// One wave per batch element. Lane l owns gate g=l&3 of hidden unit k=l>>2,
// i.e. weight row (g*16 + k) of each [64,16] matrix, held in registers.
// h1/h2 state lives as 16 wave-uniform values (readlane -> SGPR), so the
// recurrent dot products are plain v_fmac v, s, v.
__global__ __launch_bounds__(256) void lstm_fused_kernel(
    const float* __restrict__ x,
    const float* __restrict__ W_ih0, const float* __restrict__ W_hh0,
    const float* __restrict__ b_ih0, const float* __restrict__ b_hh0,
    const float* __restrict__ W_ih1, const float* __restrict__ W_hh1,
    const float* __restrict__ b_ih1, const float* __restrict__ b_hh1,
    const float* __restrict__ W_proj, const float* __restrict__ b_proj,
    const float* __restrict__ ln_g, const float* __restrict__ ln_b,
    float* __restrict__ out)
{
    const int lane = threadIdx.x & 63;
    const int wave = threadIdx.x >> 6;
    const int b    = blockIdx.x * 4 + wave;

    const int g   = lane & 3;        // 0=i 1=f 2=g 3=o
    const int k   = lane >> 2;       // hidden unit 0..15
    const int row = g * HH + k;      // row in [4H,H] weights (PyTorch order)

    // ---- load this lane's weight rows into VGPRs (one-time) ----
    float wih0[HH], whh0[HH], wih1[HH], whh1[HH];
#pragma unroll
    for (int q = 0; q < 4; ++q) {
        ((float4*)wih0)[q] = ((const float4*)(W_ih0 + row * HH))[q];
        ((float4*)whh0)[q] = ((const float4*)(W_hh0 + row * HH))[q];
        ((float4*)wih1)[q] = ((const float4*)(W_ih1 + row * HH))[q];
        ((float4*)whh1)[q] = ((const float4*)(W_hh1 + row * HH))[q];
    }
    const float bias0 = b_ih0[row] + b_hh0[row];
    const float bias1 = b_ih1[row] + b_hh1[row];

    // activation constants: sigmoid for i,f,o ; tanh for g (=2*sig(2x)-1)
    const bool  isg    = (g == 2);
    const float sc_in  = isg ? (-2.0f * LOG2E) : (-LOG2E);
    const float sc_out = isg ? 2.0f : 1.0f;
    const float sh_out = isg ? 1.0f : 0.0f;

    // ---- state ----
    float c1 = 0.0f, c2 = 0.0f;
    float h1s[HH], h2s[HH];
#pragma unroll
    for (int j = 0; j < HH; ++j) { h1s[j] = 0.0f; h2s[j] = 0.0f; }

    // x stream: lane l reads x[b][t][l&15]; readlane(j) broadcasts x_t[j]
    const float* xp = x + (size_t)b * TT * HH + (lane & 15);
    float xv = xp[0];

    for (int t = 0; t < TT; ++t) {
        const float* xpn = (t + 1 < TT) ? (xp + HH) : xp;  // clamped prefetch
        const float xnext = xpn[0];

        // ================= layer 1 =================
        float a = bias0;
#pragma unroll
        for (int j = 0; j < HH; ++j) a += rl(xv, j) * wih0[j];
#pragma unroll
        for (int j = 0; j < HH; ++j) a += h1s[j] * whh0[j];

        float act = frcp(1.0f + fexp2(a * sc_in)) * sc_out - sh_out;

        float iv = quad_bcast<0x00>(act);
        float fv = quad_bcast<0x55>(act);
        float gv = quad_bcast<0xAA>(act);
        float ov = quad_bcast<0xFF>(act);

        c1 = fv * c1 + iv * gv;
        const float h1n = ov * ftanh(c1);
#pragma unroll
        for (int j = 0; j < HH; ++j) h1s[j] = rl(h1n, 4 * j);

        // ================= layer 2 =================
        float a2 = bias1;
#pragma unroll
        for (int j = 0; j < HH; ++j) a2 += h1s[j] * wih1[j];
#pragma unroll
        for (int j = 0; j < HH; ++j) a2 += h2s[j] * whh1[j];

        float act2 = frcp(1.0f + fexp2(a2 * sc_in)) * sc_out - sh_out;

        float iv2 = quad_bcast<0x00>(act2);
        float fv2 = quad_bcast<0x55>(act2);
        float gv2 = quad_bcast<0xAA>(act2);
        float ov2 = quad_bcast<0xFF>(act2);

        c2 = fv2 * c2 + iv2 * gv2;
        const float h2n = ov2 * ftanh(c2);
#pragma unroll
        for (int j = 0; j < HH; ++j) h2s[j] = rl(h2n, 4 * j);

        xv = xnext;
        xp += HH;
    }

    // ---- epilogue: z = h2 @ W_proj^T + b_proj ; LayerNorm ; tanh ----
    const int u = lane & 15;   // output unit (replicated x4 across the wave)
    float z = b_proj[u];
#pragma unroll
    for (int j = 0; j < HH; ++j) z += h2s[j] * W_proj[u * HH + j];

    // reduce across the 16-lane group (xor masks 1,2,4,8 stay in-group)
    float s = z;
    s += __shfl_xor(s, 1); s += __shfl_xor(s, 2);
    s += __shfl_xor(s, 4); s += __shfl_xor(s, 8);
    const float mu = s * (1.0f / 16.0f);

    const float d = z - mu;
    float q2 = d * d;
    q2 += __shfl_xor(q2, 1); q2 += __shfl_xor(q2, 2);
    q2 += __shfl_xor(q2, 4); q2 += __shfl_xor(q2, 8);
    const float var = q2 * (1.0f / 16.0f);

    const float rs  = frsq(var + 1e-5f);
    const float y   = d * rs * ln_g[u] + ln_b[u];
    const float res = ftanh(y);

    if (lane < 16) out[(size_t)b * HH + lane] = res;
}

extern "C" void kernel_launch(void* const* d_in, const int* in_sizes, int n_in,
                              void* d_out, int out_size, void* d_ws, size_t ws_size,
                              hipStream_t stream) {
    const float* x      = (const float*)d_in[0];
    const float* W_ih0  = (const float*)d_in[1];
    const float* W_hh0  = (const float*)d_in[2];
    const float* b_ih0  = (const float*)d_in[3];
    const float* b_hh0  = (const float*)d_in[4];
    const float* W_ih1  = (const float*)d_in[5];
    const float* W_hh1  = (const float*)d_in[6];
    const float* b_ih1  = (const float*)d_in[7];
    const float* b_hh1  = (const float*)d_in[8];
    const float* W_proj = (const float*)d_in[9];
    const float* b_proj = (const float*)d_in[10];
    const float* ln_g   = (const float*)d_in[11];
    const float* ln_b   = (const float*)d_in[12];
    float* out = (float*)d_out;

    const int B = in_sizes[0] / (TT * HH);   // 4096
    dim3 grid(B / 4), block(256);            // one wave per batch element
    hipLaunchKernelGGL(lstm_fused_kernel, grid, block, 0, stream,
                       x, W_ih0, W_hh0, b_ih0, b_hh0,
                       W_ih1, W_hh1, b_ih1, b_hh1,
                       W_proj, b_proj, ln_g, ln_b, out);
}

// Round 2
// 513.449 us; speedup vs baseline: 1.4541x; 1.4541x over previous
//
#include <hip/hip_runtime.h>
#include <cstddef>

#define HH 16
#define TT 512
#define STG 16   // timesteps staged into LDS per global load
#define LOG2E 1.44269504088896340736f

typedef float v2f __attribute__((ext_vector_type(2)));
typedef float v4f __attribute__((ext_vector_type(4)));

static __device__ __forceinline__ float fexp2(float x){ return __builtin_amdgcn_exp2f(x); }
static __device__ __forceinline__ float frcp (float x){ return __builtin_amdgcn_rcpf(x); }
static __device__ __forceinline__ float frsq (float x){ return __builtin_amdgcn_rsqf(x); }

// tanh(c) = 2/(1+exp(-2c)) - 1 ; saturates correctly (rcp(inf)=0)
static __device__ __forceinline__ float ftanh(float c){
    return frcp(1.0f + fexp2(c * (-2.0f*LOG2E))) * 2.0f - 1.0f;
}

// broadcast within each quad of lanes (VALU DPP)
template<int CTRL>
static __device__ __forceinline__ float qb(float v){
    return __builtin_bit_cast(float,
        __builtin_amdgcn_update_dpp(0, __builtin_bit_cast(int,v), CTRL, 0xF, 0xF, true));
}

static __device__ __forceinline__ v2f pkfma(v2f a, v2f b, v2f c){
    return __builtin_elementwise_fma(a, b, c);  // -> v_pk_fma_f32
}

// 16-float dot: a[] in regs (from LDS broadcast), w[] in regs. 8 pk_fma.
static __device__ __forceinline__ float dot16v(const v4f* a, const v4f* w){
    v2f s0 = {0.f, 0.f}, s1 = {0.f, 0.f};
    s0 = pkfma(a[0].lo, w[0].lo, s0);  s1 = pkfma(a[0].hi, w[0].hi, s1);
    s0 = pkfma(a[1].lo, w[1].lo, s0);  s1 = pkfma(a[1].hi, w[1].hi, s1);
    s0 = pkfma(a[2].lo, w[2].lo, s0);  s1 = pkfma(a[2].hi, w[2].hi, s1);
    s0 = pkfma(a[3].lo, w[3].lo, s0);  s1 = pkfma(a[3].hi, w[3].hi, s1);
    v2f s = s0 + s1;                    // v_pk_add_f32
    return s.x + s.y;
}

// One wave per batch element. Lane l owns gate g=l&3 of hidden unit k=l>>2.
// x and h are broadcast to all lanes through per-wave LDS regions (LDS pipe),
// not v_readlane (VALU pipe). Dots are v_pk_fma_f32.
__global__ __launch_bounds__(256, 4) void lstm_fused_kernel(
    const float* __restrict__ x,
    const float* __restrict__ W_ih0, const float* __restrict__ W_hh0,
    const float* __restrict__ b_ih0, const float* __restrict__ b_hh0,
    const float* __restrict__ W_ih1, const float* __restrict__ W_hh1,
    const float* __restrict__ b_ih1, const float* __restrict__ b_hh1,
    const float* __restrict__ W_proj, const float* __restrict__ b_proj,
    const float* __restrict__ ln_g, const float* __restrict__ ln_b,
    float* __restrict__ out)
{
    const int lane = threadIdx.x & 63;
    const int wave = threadIdx.x >> 6;
    const int b    = blockIdx.x * 4 + wave;

    const int g   = lane & 3;        // 0=i 1=f 2=g 3=o
    const int k   = lane >> 2;       // hidden unit 0..15
    const int row = g * HH + k;      // row in [4H,H] weights (PyTorch order)

    // per-wave LDS: 256 floats x-stage + 16 h1 + 16 h2
    __shared__ float sh[4 * 288];
    float* xw  = sh + wave * 288;
    float* h1w = xw + 256;
    float* h2w = h1w + 16;

    // ---- weights into VGPRs as v4f (pairs feed v_pk_fma via .lo/.hi) ----
    v4f wih0[4], whh0[4], wih1[4], whh1[4];
#pragma unroll
    for (int q = 0; q < 4; ++q) {
        wih0[q] = ((const v4f*)(W_ih0 + row * HH))[q];
        whh0[q] = ((const v4f*)(W_hh0 + row * HH))[q];
        wih1[q] = ((const v4f*)(W_ih1 + row * HH))[q];
        whh1[q] = ((const v4f*)(W_hh1 + row * HH))[q];
    }
    const float bias0 = b_ih0[row] + b_hh0[row];
    const float bias1 = b_ih1[row] + b_hh1[row];

    // activation constants: sigmoid for i,f,o ; tanh for g (=2*sig(2x)-1)
    const bool  isg    = (g == 2);
    const float sc_in  = isg ? (-2.0f * LOG2E) : (-LOG2E);
    const float sc_out = isg ? 2.0f : 1.0f;
    const float sh_out = isg ? 1.0f : 0.0f;

    // ---- state: c per-lane; h as broadcast register copies (v4f[4]) ----
    float c1 = 0.0f, c2 = 0.0f;
    v4f h1a[4], h2a[4];
#pragma unroll
    for (int q = 0; q < 4; ++q) { h1a[q] = (v4f)(0.f); h2a[q] = (v4f)(0.f); }

    const float* xb = x + (size_t)b * TT * HH;

    // prefetch stage 0: 64 lanes x float4 = 16 timesteps (1 KiB contiguous)
    v4f xs = *(const v4f*)(xb + lane * 4);

    for (int t0 = 0; t0 < TT; t0 += STG) {
        *(v4f*)(xw + lane * 4) = xs;               // stage into LDS
        asm volatile("" ::: "memory");
        if (t0 + STG < TT)                          // prefetch next stage
            xs = *(const v4f*)(xb + (size_t)(t0 + STG) * HH + lane * 4);

#pragma unroll
        for (int ti = 0; ti < STG; ++ti) {
            // x_t broadcast: 4x same-address ds_read_b128
            v4f xa[4];
            {
                const v4f* p = (const v4f*)(xw + ti * HH);
                xa[0] = p[0]; xa[1] = p[1]; xa[2] = p[2]; xa[3] = p[3];
            }

            // ================= layer 1 =================
            float a1 = bias0 + dot16v(xa, wih0) + dot16v(h1a, whh0);
            float act1 = frcp(1.0f + fexp2(a1 * sc_in)) * sc_out - sh_out;
            float i1 = qb<0x00>(act1), f1 = qb<0x55>(act1);
            float g1 = qb<0xAA>(act1), o1 = qb<0xFF>(act1);
            c1 = __builtin_fmaf(f1, c1, i1 * g1);
            float h1n = o1 * ftanh(c1);

            h1w[k] = h1n;                          // all 4 lanes of quad k write same value
            asm volatile("" ::: "memory");
            {
                const v4f* p = (const v4f*)h1w;    // broadcast back: 4x ds_read_b128
                h1a[0] = p[0]; h1a[1] = p[1]; h1a[2] = p[2]; h1a[3] = p[3];
            }

            // ================= layer 2 =================
            float a2 = bias1 + dot16v(h1a, wih1) + dot16v(h2a, whh1);
            float act2 = frcp(1.0f + fexp2(a2 * sc_in)) * sc_out - sh_out;
            float i2 = qb<0x00>(act2), f2 = qb<0x55>(act2);
            float g2 = qb<0xAA>(act2), o2 = qb<0xFF>(act2);
            c2 = __builtin_fmaf(f2, c2, i2 * g2);
            float h2n = o2 * ftanh(c2);

            h2w[k] = h2n;
            asm volatile("" ::: "memory");
            {
                const v4f* p = (const v4f*)h2w;
                h2a[0] = p[0]; h2a[1] = p[1]; h2a[2] = p[2]; h2a[3] = p[3];
            }
        }
        asm volatile("" ::: "memory");             // keep next stage write below these reads
    }

    // ---- epilogue: z = h2 @ W_proj^T + b_proj ; LayerNorm ; tanh ----
    const int u = lane & 15;   // output unit (replicated x4 across the wave)
    v4f wp[4];
#pragma unroll
    for (int q = 0; q < 4; ++q) wp[q] = ((const v4f*)(W_proj + u * HH))[q];
    float z = b_proj[u] + dot16v(h2a, wp);

    // stats across the 16-lane group (xor masks 1,2,4,8 stay in-group)
    float s = z;
    s += __shfl_xor(s, 1); s += __shfl_xor(s, 2);
    s += __shfl_xor(s, 4); s += __shfl_xor(s, 8);
    const float mu = s * (1.0f / 16.0f);

    const float d = z - mu;
    float q2 = d * d;
    q2 += __shfl_xor(q2, 1); q2 += __shfl_xor(q2, 2);
    q2 += __shfl_xor(q2, 4); q2 += __shfl_xor(q2, 8);
    const float var = q2 * (1.0f / 16.0f);

    const float rs  = frsq(var + 1e-5f);
    const float y   = d * rs * ln_g[u] + ln_b[u];
    const float res = ftanh(y);

    if (lane < 16) out[(size_t)b * HH + lane] = res;
}

extern "C" void kernel_launch(void* const* d_in, const int* in_sizes, int n_in,
                              void* d_out, int out_size, void* d_ws, size_t ws_size,
                              hipStream_t stream) {
    const float* x      = (const float*)d_in[0];
    const float* W_ih0  = (const float*)d_in[1];
    const float* W_hh0  = (const float*)d_in[2];
    const float* b_ih0  = (const float*)d_in[3];
    const float* b_hh0  = (const float*)d_in[4];
    const float* W_ih1  = (const float*)d_in[5];
    const float* W_hh1  = (const float*)d_in[6];
    const float* b_ih1  = (const float*)d_in[7];
    const float* b_hh1  = (const float*)d_in[8];
    const float* W_proj = (const float*)d_in[9];
    const float* b_proj = (const float*)d_in[10];
    const float* ln_g   = (const float*)d_in[11];
    const float* ln_b   = (const float*)d_in[12];
    float* out = (float*)d_out;

    const int B = in_sizes[0] / (TT * HH);   // 4096
    dim3 grid(B / 4), block(256);            // one wave per batch element
    hipLaunchKernelGGL(lstm_fused_kernel, grid, block, 0, stream,
                       x, W_ih0, W_hh0, b_ih0, b_hh0,
                       W_ih1, W_hh1, b_ih1, b_hh1,
                       W_proj, b_proj, ln_g, ln_b, out);
}

// Round 3
// 491.551 us; speedup vs baseline: 1.5189x; 1.0445x over previous
//
#include <hip/hip_runtime.h>
#include <cstddef>

#define HH 16
#define TT 512
#define STG 16           // timesteps per LDS x-stage
#define NSTG (TT / STG)  // 32 stages
#define LOG2E 1.44269504088896340736f

typedef float v2f __attribute__((ext_vector_type(2)));
typedef float v4f __attribute__((ext_vector_type(4)));

static __device__ __forceinline__ float fexp2(float x){ return __builtin_amdgcn_exp2f(x); }
static __device__ __forceinline__ float frcp (float x){ return __builtin_amdgcn_rcpf(x); }
static __device__ __forceinline__ float frsq (float x){ return __builtin_amdgcn_rsqf(x); }

// tanh(c) = 2/(1+exp(-2c)) - 1 ; saturates correctly (rcp(inf)=0)
static __device__ __forceinline__ float ftanh(float c){
    return frcp(1.0f + fexp2(c * (-2.0f*LOG2E))) * 2.0f - 1.0f;
}

// broadcast within each quad of lanes (VALU DPP)
template<int CTRL>
static __device__ __forceinline__ float qb(float v){
    return __builtin_bit_cast(float,
        __builtin_amdgcn_update_dpp(0, __builtin_bit_cast(int,v), CTRL, 0xF, 0xF, true));
}

static __device__ __forceinline__ v2f pkfma(v2f a, v2f b, v2f c){
    return __builtin_elementwise_fma(a, b, c);  // -> v_pk_fma_f32
}

// accumulate a 16-float dot into two v2f partials (8 pk_fma)
static __device__ __forceinline__ void dot16_acc(const v4f* a, const v4f* w, v2f& s0, v2f& s1){
    s0 = pkfma(a[0].lo, w[0].lo, s0);  s1 = pkfma(a[0].hi, w[0].hi, s1);
    s0 = pkfma(a[1].lo, w[1].lo, s0);  s1 = pkfma(a[1].hi, w[1].hi, s1);
    s0 = pkfma(a[2].lo, w[2].lo, s0);  s1 = pkfma(a[2].hi, w[2].hi, s1);
    s0 = pkfma(a[3].lo, w[3].lo, s0);  s1 = pkfma(a[3].hi, w[3].hi, s1);
}

static __device__ __forceinline__ void ld4(v4f* dst, const float* p){
    const v4f* q = (const v4f*)p;
    dst[0] = q[0]; dst[1] = q[1]; dst[2] = q[2]; dst[3] = q[3];
}

// One wave per batch element. Lane l owns gate g=l&3 of hidden unit k=l>>2.
// Software-pipelined: layer 1 runs ONE timestep ahead of layer 2, so every
// LDS broadcast round-trip (h1, h2, x) is issued ~a-layer's-worth of VALU
// work before its consumer instead of being a serial dependence.
__global__ __launch_bounds__(256, 4) void lstm_fused_kernel(
    const float* __restrict__ x,
    const float* __restrict__ W_ih0, const float* __restrict__ W_hh0,
    const float* __restrict__ b_ih0, const float* __restrict__ b_hh0,
    const float* __restrict__ W_ih1, const float* __restrict__ W_hh1,
    const float* __restrict__ b_ih1, const float* __restrict__ b_hh1,
    const float* __restrict__ W_proj, const float* __restrict__ b_proj,
    const float* __restrict__ ln_g, const float* __restrict__ ln_b,
    float* __restrict__ out)
{
    const int lane = threadIdx.x & 63;
    const int wave = threadIdx.x >> 6;
    const int b    = blockIdx.x * 4 + wave;

    const int g   = lane & 3;        // 0=i 1=f 2=g 3=o
    const int k   = lane >> 2;       // hidden unit 0..15
    const int row = g * HH + k;      // row in [4H,H] weights (PyTorch order)

    // per-wave LDS: two 256-float x-stages (ping-pong) + h1[16] + h2[16]
    __shared__ float sh[4 * 544];
    float* xb0 = sh + wave * 544;
    float* xb1 = xb0 + 256;
    float* h1w = xb1 + 256;
    float* h2w = h1w + 16;

    // ---- weights into VGPRs as v4f (pairs feed v_pk_fma via .lo/.hi) ----
    v4f wih0[4], whh0[4], wih1[4], whh1[4];
#pragma unroll
    for (int q = 0; q < 4; ++q) {
        wih0[q] = ((const v4f*)(W_ih0 + row * HH))[q];
        whh0[q] = ((const v4f*)(W_hh0 + row * HH))[q];
        wih1[q] = ((const v4f*)(W_ih1 + row * HH))[q];
        whh1[q] = ((const v4f*)(W_hh1 + row * HH))[q];
    }
    const float bias0 = b_ih0[row] + b_hh0[row];
    const float bias1 = b_ih1[row] + b_hh1[row];

    // activation constants: sigmoid for i,f,o ; tanh for g (=2*sig(2x)-1)
    const bool  isg    = (g == 2);
    const float sc_in  = isg ? (-2.0f * LOG2E) : (-LOG2E);
    const float sc_out = isg ? 2.0f : 1.0f;
    const float sh_out = isg ? 1.0f : 0.0f;

    const float* xg = x + (size_t)b * TT * HH;

    // ================= prologue =================
    v4f xs = *(const v4f*)(xg + lane * 4);     // global stage 0
    *(v4f*)(xb0 + lane * 4) = xs;              // LDS stage 0
    xs = *(const v4f*)(xg + 256 + lane * 4);   // prefetch global stage 1

    v4f xa[4];
    ld4(xa, xb0);                              // broadcast x(0)

    float c1, c2 = 0.0f;
    v4f h1a[4], h2a[4];
#pragma unroll
    for (int q = 0; q < 4; ++q) h2a[q] = (v4f)(0.f);

    // layer-1 step 0 (h1(-1) = 0: skip hh dot)
    {
        v2f p0 = {bias0, 0.f}, p1 = {0.f, 0.f};
        dot16_acc(xa, wih0, p0, p1);
        v2f ps = p0 + p1;
        float a1 = ps.x + ps.y;
        float act1 = frcp(1.0f + fexp2(a1 * sc_in)) * sc_out - sh_out;
        float i1 = qb<0x00>(act1), g1 = qb<0xAA>(act1), o1 = qb<0xFF>(act1);
        c1 = i1 * g1;
        float h1n = o1 * ftanh(c1);
        h1w[k] = h1n;
        ld4(h1a, h1w);                         // broadcast h1(0)
        ld4(xa, xb0 + HH);                     // broadcast x(1)
    }

    // ================= main loop =================
    // iter t: layer1 computes h1(t+1) [xa=x(t+1), h1a=h1(t)];
    //         layer2 computes h2(t)   [h1a=h1(t), h2a=h2(t-1)]
    for (int s = 0; s < NSTG; ++s) {
        float* cur = (s & 1) ? xb1 : xb0;
        float* nxt = (s & 1) ? xb0 : xb1;

        *(v4f*)(nxt + lane * 4) = xs;          // LDS stage s+1
        const int sp = (s + 2 < NSTG) ? (s + 2) : (NSTG - 1);
        xs = *(const v4f*)(xg + (size_t)sp * 256 + lane * 4);  // prefetch s+2

#pragma unroll
        for (int ti = 0; ti < STG; ++ti) {
            // ---- layer 1, step t+1 ----
            v2f p0 = {bias0, 0.f}, p1 = {0.f, 0.f};
            dot16_acc(xa, wih0, p0, p1);
            dot16_acc(h1a, whh0, p0, p1);
            v2f ps = p0 + p1;
            float a1 = ps.x + ps.y;
            float act1 = frcp(1.0f + fexp2(a1 * sc_in)) * sc_out - sh_out;
            float i1 = qb<0x00>(act1), f1 = qb<0x55>(act1);
            float g1 = qb<0xAA>(act1), o1 = qb<0xFF>(act1);
            c1 = __builtin_fmaf(f1, c1, i1 * g1);
            float h1n = o1 * ftanh(c1);
            h1w[k] = h1n;                      // publish h1(t+1)

            // ---- layer 2 part A: h1(t) · W_ih1 (last use of h1a) ----
            v2f q0 = {bias1, 0.f}, q1 = {0.f, 0.f};
            dot16_acc(h1a, wih1, q0, q1);

            ld4(h1a, h1w);                     // broadcast h1(t+1)  [next iter]
            // broadcast x(t+2) [next iter]; ti=14,15 cross into next stage
            ld4(xa, (ti <= 13) ? (cur + (ti + 2) * HH) : (nxt + (ti - 14) * HH));

            // ---- layer 2 part B: h2(t-1) · W_hh1 ----
            dot16_acc(h2a, whh1, q0, q1);
            v2f qs = q0 + q1;
            float a2 = qs.x + qs.y;
            float act2 = frcp(1.0f + fexp2(a2 * sc_in)) * sc_out - sh_out;
            float i2 = qb<0x00>(act2), f2 = qb<0x55>(act2);
            float g2 = qb<0xAA>(act2), o2 = qb<0xFF>(act2);
            c2 = __builtin_fmaf(f2, c2, i2 * g2);
            float h2n = o2 * ftanh(c2);
            h2w[k] = h2n;                      // publish h2(t)
            ld4(h2a, h2w);                     // broadcast h2(t)    [next iter]
        }
    }

    // ---- epilogue: z = h2(T-1) @ W_proj^T + b_proj ; LayerNorm ; tanh ----
    const int u = lane & 15;   // output unit (replicated x4 across the wave)
    v4f wp[4];
#pragma unroll
    for (int q = 0; q < 4; ++q) wp[q] = ((const v4f*)(W_proj + u * HH))[q];
    v2f z0 = {0.f, 0.f}, z1 = {0.f, 0.f};
    dot16_acc(h2a, wp, z0, z1);
    v2f zs = z0 + z1;
    float z = b_proj[u] + zs.x + zs.y;

    // stats across the 16-lane group (xor masks 1,2,4,8 stay in-group)
    float sacc = z;
    sacc += __shfl_xor(sacc, 1); sacc += __shfl_xor(sacc, 2);
    sacc += __shfl_xor(sacc, 4); sacc += __shfl_xor(sacc, 8);
    const float mu = sacc * (1.0f / 16.0f);

    const float d = z - mu;
    float q2 = d * d;
    q2 += __shfl_xor(q2, 1); q2 += __shfl_xor(q2, 2);
    q2 += __shfl_xor(q2, 4); q2 += __shfl_xor(q2, 8);
    const float var = q2 * (1.0f / 16.0f);

    const float rs  = frsq(var + 1e-5f);
    const float y   = d * rs * ln_g[u] + ln_b[u];
    const float res = ftanh(y);

    if (lane < 16) out[(size_t)b * HH + lane] = res;
}

extern "C" void kernel_launch(void* const* d_in, const int* in_sizes, int n_in,
                              void* d_out, int out_size, void* d_ws, size_t ws_size,
                              hipStream_t stream) {
    const float* x      = (const float*)d_in[0];
    const float* W_ih0  = (const float*)d_in[1];
    const float* W_hh0  = (const float*)d_in[2];
    const float* b_ih0  = (const float*)d_in[3];
    const float* b_hh0  = (const float*)d_in[4];
    const float* W_ih1  = (const float*)d_in[5];
    const float* W_hh1  = (const float*)d_in[6];
    const float* b_ih1  = (const float*)d_in[7];
    const float* b_hh1  = (const float*)d_in[8];
    const float* W_proj = (const float*)d_in[9];
    const float* b_proj = (const float*)d_in[10];
    const float* ln_g   = (const float*)d_in[11];
    const float* ln_b   = (const float*)d_in[12];
    float* out = (float*)d_out;

    const int B = in_sizes[0] / (TT * HH);   // 4096
    dim3 grid(B / 4), block(256);            // one wave per batch element
    hipLaunchKernelGGL(lstm_fused_kernel, grid, block, 0, stream,
                       x, W_ih0, W_hh0, b_ih0, b_hh0,
                       W_ih1, W_hh1, b_ih1, b_hh1,
                       W_proj, b_proj, ln_g, ln_b, out);
}